// Round 1
// baseline (661.249 us; speedup 1.0000x reference)
//
#include <hip/hip_runtime.h>
#include <math.h>

#define BB 4
#define CIN 64
#define HX 48
#define WX 48
#define OMC 216
#define HY 96
#define WY 96
#define NDG 8
#define CPG 8
#define KK2 9
#define OUTC 64

// ---------------- Kernel 1: 3x3 conv, pad=1, 64->216 ch @ 48x48 ----------------
__global__ __launch_bounds__(256) void conv_om_kernel(
    const float* __restrict__ x, const float* __restrict__ w,
    const float* __restrict__ bias, float* __restrict__ om) {
  __shared__ float ws[CIN * KK2];  // 576 floats
  int blk = blockIdx.x;
  int tile = blk % 9;
  int oc = (blk / 9) % OMC;
  int b = blk / (9 * OMC);
  for (int i = threadIdx.x; i < CIN * KK2; i += 256) ws[i] = w[oc * CIN * KK2 + i];
  __syncthreads();
  int p = tile * 256 + threadIdx.x;   // 0..2303
  int h = p / WX, wcol = p % WX;
  const float* xb = x + b * CIN * HX * WX;
  float acc = bias[oc];
  for (int ic = 0; ic < CIN; ++ic) {
    const float* xc = xb + ic * HX * WX;
#pragma unroll
    for (int ky = 0; ky < 3; ++ky) {
      int hy = h + ky - 1;
      if ((unsigned)hy < HX) {
        const float* row = xc + hy * WX;
#pragma unroll
        for (int kx = 0; kx < 3; ++kx) {
          int wx = wcol + kx - 1;
          if ((unsigned)wx < WX) acc += row[wx] * ws[ic * 9 + ky * 3 + kx];
        }
      }
    }
  }
  om[b * OMC * HX * WX + oc * HX * WX + p] = acc;
}

// ---------------- Kernel 2: repack w_dc (64x576) -> wt4[j4][o][4] ----------------
__global__ __launch_bounds__(256) void transpose_w_kernel(
    const float* __restrict__ wdc, float* __restrict__ wt4) {
  int idx = blockIdx.x * 256 + threadIdx.x;  // 0..36863
  int j4 = idx >> 8;
  int r = idx & 255;
  int o = r >> 2;
  int jj = r & 3;
  wt4[idx] = wdc[o * 576 + j4 * 4 + jj];
}

// ---------------- Kernel 3: fused resize + sigmoid + mod-deform-conv + relu ------
__global__ __launch_bounds__(256) void deform_kernel(
    const float* __restrict__ y, const float* __restrict__ om,
    const float* __restrict__ wt4, const float* __restrict__ bdc,
    float* __restrict__ out) {
  __shared__ float s_oy[4][72];
  __shared__ float s_ox[4][72];
  __shared__ float s_m[4][72];
  __shared__ float s_val[4][576];

  int wv = threadIdx.x >> 6;
  int lane = threadIdx.x & 63;
  int pid = blockIdx.x * 4 + wv;      // 0..36863
  int b = pid / (HY * WY);
  int rem = pid % (HY * WY);
  int h = rem / WY;
  int w = rem % WY;

  // bilinear-resize coords (half-pixel, scale 0.5, clamp at 0)
  float sh = fmaxf(h * 0.5f - 0.25f, 0.0f);
  float sw = fmaxf(w * 0.5f - 0.25f, 0.0f);
  int i0h = (int)floorf(sh);
  float th = sh - (float)i0h;
  int i1h = min(i0h + 1, HX - 1);
  int i0w = (int)floorf(sw);
  float tw = sw - (float)i0w;
  int i1w = min(i0w + 1, WX - 1);
  float w00 = (1.0f - th) * (1.0f - tw);
  float w01 = (1.0f - th) * tw;
  float w10 = th * (1.0f - tw);
  float w11 = th * tw;

  const float* omb = om + b * OMC * HX * WX;

  // Phase 0: resize offsets + mask for the 72 (g,k) items of this pixel
  for (int idx = lane; idx < NDG * KK2; idx += 64) {
    int g = idx / 9, k = idx % 9;
    int chy = g * 18 + k * 2;
    const float* c0 = omb + chy * HX * WX;
    const float* c1 = omb + (chy + 1) * HX * WX;
    const float* cm = omb + (144 + g * 9 + k) * HX * WX;
    int a00 = i0h * WX + i0w, a01 = i0h * WX + i1w;
    int a10 = i1h * WX + i0w, a11 = i1h * WX + i1w;
    s_oy[wv][idx] = w00 * c0[a00] + w01 * c0[a01] + w10 * c0[a10] + w11 * c0[a11];
    s_ox[wv][idx] = w00 * c1[a00] + w01 * c1[a01] + w10 * c1[a10] + w11 * c1[a11];
    float mv = w00 * cm[a00] + w01 * cm[a01] + w10 * cm[a10] + w11 * cm[a11];
    s_m[wv][idx] = 1.0f / (1.0f + expf(-mv));
  }
  __syncthreads();

  // Phase 1: lane = input channel (g*8+c); 9 taps; 4-corner gather from y
  {
    int g = lane >> 3;
    const float* yc = y + (size_t)(b * OUTC + lane) * HY * WY;
#pragma unroll
    for (int k = 0; k < 9; ++k) {
      float oy = s_oy[wv][g * 9 + k];
      float ox = s_ox[wv][g * 9 + k];
      float mk = s_m[wv][g * 9 + k];
      float py = (float)(h + (k / 3) - 1) + oy;
      float px = (float)(w + (k % 3) - 1) + ox;
      float y0f = floorf(py), x0f = floorf(px);
      float ty = py - y0f, tx = px - x0f;
      int y0 = (int)y0f, x0 = (int)x0f;
      int y1 = y0 + 1, x1 = x0 + 1;
      float v00 = ((unsigned)y0 < HY && (unsigned)x0 < WY) ? yc[y0 * WY + x0] : 0.0f;
      float v01 = ((unsigned)y0 < HY && (unsigned)x1 < WY) ? yc[y0 * WY + x1] : 0.0f;
      float v10 = ((unsigned)y1 < HY && (unsigned)x0 < WY) ? yc[y1 * WY + x0] : 0.0f;
      float v11 = ((unsigned)y1 < HY && (unsigned)x1 < WY) ? yc[y1 * WY + x1] : 0.0f;
      float wy0 = 1.0f - ty, wx0 = 1.0f - tx;
      float v = (v00 * wy0 * wx0 + v01 * wy0 * tx + v10 * ty * wx0 + v11 * ty * tx) * mk;
      s_val[wv][lane * 9 + k] = v;
    }
  }
  __syncthreads();

  // Phase 2: lane = output channel; 576-long dot via float4s
  {
    float acc = 0.0f;
    const float4* wtv = (const float4*)wt4;
    const float4* valv = (const float4*)(&s_val[wv][0]);
#pragma unroll 4
    for (int j4 = 0; j4 < 144; ++j4) {
      float4 wt = wtv[j4 * 64 + lane];
      float4 v4 = valv[j4];
      acc += wt.x * v4.x + wt.y * v4.y + wt.z * v4.z + wt.w * v4.w;
    }
    acc += bdc[lane];
    out[(size_t)(b * OUTC + lane) * HY * WY + h * WY + w] = fmaxf(acc, 0.0f);
  }
}

extern "C" void kernel_launch(void* const* d_in, const int* in_sizes, int n_in,
                              void* d_out, int out_size, void* d_ws, size_t ws_size,
                              hipStream_t stream) {
  const float* x = (const float*)d_in[0];
  const float* y = (const float*)d_in[1];
  const float* w_om = (const float*)d_in[2];
  const float* b_om = (const float*)d_in[3];
  const float* w_dc = (const float*)d_in[4];
  const float* b_dc = (const float*)d_in[5];
  float* out = (float*)d_out;

  float* om = (float*)d_ws;                          // 4*216*48*48 = 1,990,656 f
  float* wt4 = om + (size_t)BB * OMC * HX * WX;      // 36,864 f

  conv_om_kernel<<<BB * OMC * 9, 256, 0, stream>>>(x, w_om, b_om, om);
  transpose_w_kernel<<<144, 256, 0, stream>>>(w_dc, wt4);
  deform_kernel<<<BB * HY * WY / 4, 256, 0, stream>>>(y, om, wt4, b_dc, out);
}

// Round 2
// 189.672 us; speedup vs baseline: 3.4863x; 3.4863x over previous
//
#include <hip/hip_runtime.h>
#include <math.h>

#define HX 48
#define WX 48
#define OMC 216
#define HY 96
#define WY 96

// ---------- prep: wt2[k][ic][oc256] from w_om[216][64][9]; wt1[k][c][oc64] from w_dc[64][64][9]
__global__ __launch_bounds__(256) void prep_w_kernel(
    const float* __restrict__ w_om, const float* __restrict__ w_dc,
    float* __restrict__ wt2, float* __restrict__ wt1) {
  int idx = blockIdx.x * 256 + threadIdx.x;
  if (idx < 9 * 64 * 256) {
    int oc = idx & 255, ic = (idx >> 8) & 63, k = idx >> 14;
    wt2[idx] = (oc < OMC) ? w_om[oc * 576 + ic * 9 + k] : 0.0f;
  } else {
    int j = idx - 9 * 64 * 256;  // < 36864
    int oc = j & 63, c = (j >> 6) & 63, k = j >> 12;
    wt1[j] = w_dc[oc * 576 + c * 9 + k];
  }
}

// ---------- y[b][c][p] -> yt[b][p][c], 64x64 tiles through LDS
__global__ __launch_bounds__(256) void ytr_kernel(const float* __restrict__ y,
                                                  float* __restrict__ yt) {
  __shared__ float tile[64][65];
  int blk = blockIdx.x;          // 576 = 4b * 144
  int b = blk / 144;
  int p0 = (blk % 144) * 64;
  int t = threadIdx.x;
  int pl = t & 63;
  int cb = t >> 6;
#pragma unroll
  for (int i = 0; i < 16; ++i) {
    int c = cb * 16 + i;
    tile[c][pl] = y[((size_t)(b * 64 + c)) * 9216 + p0 + pl];
  }
  __syncthreads();
  int cw = t & 63;
  int pb = t >> 6;
#pragma unroll
  for (int i = 0; i < 16; ++i) {
    int p = pb * 16 + i;
    yt[((size_t)(b * 9216 + p0 + p)) * 64 + cw] = tile[cw][p];
  }
}

// ---------- conv as GEMM: out[oc256][16px] per block, K=576 (64ic x 9 taps)
__global__ __launch_bounds__(256) void conv_gemm_kernel(
    const float* __restrict__ x, const float* __restrict__ wt2,
    const float* __restrict__ bom, float* __restrict__ om) {
  __shared__ float sval[64 * 16];
  int t = threadIdx.x;
  int blk = blockIdx.x;          // 576 = 4b * 144
  int b = blk / 144;
  int tile = blk % 144;
  int h0 = (tile / 12) * 4;
  int w0 = (tile % 12) * 4;
  int ocq = t & 63;
  int pxq = t >> 6;
  int s_ic = t >> 2;
  int s_row = t & 3;
  const float* xp = x + (size_t)b * 64 * 2304 + (size_t)s_ic * 2304;
  float acc[4][4];
#pragma unroll
  for (int i = 0; i < 4; ++i)
#pragma unroll
    for (int j = 0; j < 4; ++j) acc[i][j] = 0.0f;

  for (int k = 0; k < 9; ++k) {
    int dy = k / 3 - 1, dx = k % 3 - 1;
    __syncthreads();
    {
      int hh = h0 + s_row + dy;
      int ww = w0 + dx;
      const float* xr = xp + hh * WX;
      bool hv = (unsigned)hh < (unsigned)HX;
      float4 v;
      v.x = (hv && (unsigned)(ww + 0) < (unsigned)WX) ? xr[ww + 0] : 0.0f;
      v.y = (hv && (unsigned)(ww + 1) < (unsigned)WX) ? xr[ww + 1] : 0.0f;
      v.z = (hv && (unsigned)(ww + 2) < (unsigned)WX) ? xr[ww + 2] : 0.0f;
      v.w = (hv && (unsigned)(ww + 3) < (unsigned)WX) ? xr[ww + 3] : 0.0f;
      *(float4*)&sval[s_ic * 16 + s_row * 4] = v;
    }
    __syncthreads();
    const float* wk = wt2 + k * 64 * 256;
#pragma unroll 4
    for (int c = 0; c < 64; ++c) {
      float4 wv = *(const float4*)&wk[c * 256 + 4 * ocq];
      float4 vv = *(const float4*)&sval[c * 16 + 4 * pxq];
      acc[0][0] += wv.x * vv.x; acc[0][1] += wv.x * vv.y;
      acc[0][2] += wv.x * vv.z; acc[0][3] += wv.x * vv.w;
      acc[1][0] += wv.y * vv.x; acc[1][1] += wv.y * vv.y;
      acc[1][2] += wv.y * vv.z; acc[1][3] += wv.y * vv.w;
      acc[2][0] += wv.z * vv.x; acc[2][1] += wv.z * vv.y;
      acc[2][2] += wv.z * vv.z; acc[2][3] += wv.z * vv.w;
      acc[3][0] += wv.w * vv.x; acc[3][1] += wv.w * vv.y;
      acc[3][2] += wv.w * vv.z; acc[3][3] += wv.w * vv.w;
    }
  }
#pragma unroll
  for (int i = 0; i < 4; ++i) {
    int oc = 4 * ocq + i;
    if (oc < OMC) {
      float bv = bom[oc];
      float4 o;
      o.x = acc[i][0] + bv; o.y = acc[i][1] + bv;
      o.z = acc[i][2] + bv; o.w = acc[i][3] + bv;
      *(float4*)&om[((size_t)(b * OMC + oc)) * 2304 + (h0 + pxq) * WX + w0] = o;
    }
  }
}

// ---------- deform: fused resize+sigmoid gather -> LDS val -> GEMM (64oc x 64px, K=576)
__global__ __launch_bounds__(256) void deform_gemm_kernel(
    const float* __restrict__ yt, const float* __restrict__ om,
    const float* __restrict__ wt1, const float* __restrict__ bdc,
    float* __restrict__ out) {
  __shared__ float sval[64 * 68];
  int t = threadIdx.x;
  int blk = blockIdx.x;          // 576 = 4b * 144
  int b = blk / 144;
  int tile = blk % 144;
  int h0 = (tile / 12) * 8;
  int w0 = (tile % 12) * 8;
  int ocq = t & 15;
  int pxq = t >> 4;

  // gather role: pixel gpx of 8x8 tile, group base gb
  int gpx = t & 63;
  int gb = t >> 6;               // 0..3 ; handles gb and gb+4
  int gh = h0 + (gpx >> 3);
  int gw = w0 + (gpx & 7);

  // hoisted bilinear-resize coords for (gh,gw) at 96->48
  float sh = fmaxf(gh * 0.5f - 0.25f, 0.0f);
  float sw = fmaxf(gw * 0.5f - 0.25f, 0.0f);
  int i0h = (int)sh; float th = sh - (float)i0h;
  int i0w = (int)sw; float tw = sw - (float)i0w;
  int i1h = min(i0h + 1, HX - 1);
  int i1w = min(i0w + 1, WX - 1);
  float r00 = (1.0f - th) * (1.0f - tw), r01 = (1.0f - th) * tw;
  float r10 = th * (1.0f - tw),          r11 = th * tw;
  int a00 = i0h * WX + i0w, a01 = i0h * WX + i1w;
  int a10 = i1h * WX + i0w, a11 = i1h * WX + i1w;
  const float* omb = om + (size_t)b * OMC * 2304;
  const float* ytb = yt + (size_t)b * 9216 * 64;

  float acc[4][4];
#pragma unroll
  for (int i = 0; i < 4; ++i)
#pragma unroll
    for (int j = 0; j < 4; ++j) acc[i][j] = 0.0f;

  for (int k = 0; k < 9; ++k) {
    int dy = k / 3 - 1, dx = k % 3 - 1;
    __syncthreads();
#pragma unroll
    for (int gg = 0; gg < 2; ++gg) {
      int g = gb + gg * 4;
      const float* cy = omb + (size_t)(g * 18 + k * 2) * 2304;
      const float* cx = cy + 2304;
      const float* cm = omb + (size_t)(144 + g * 9 + k) * 2304;
      float oy = r00 * cy[a00] + r01 * cy[a01] + r10 * cy[a10] + r11 * cy[a11];
      float ox = r00 * cx[a00] + r01 * cx[a01] + r10 * cx[a10] + r11 * cx[a11];
      float mv = r00 * cm[a00] + r01 * cm[a01] + r10 * cm[a10] + r11 * cm[a11];
      float m = 1.0f / (1.0f + __expf(-mv));
      float py = (float)(gh + dy) + oy;
      float pxf = (float)(gw + dx) + ox;
      float y0f = floorf(py), x0f = floorf(pxf);
      float ty = py - y0f, tx = pxf - x0f;
      int y0 = (int)y0f, x0 = (int)x0f;
      int y1 = y0 + 1, x1 = x0 + 1;
      float w00 = (1.0f - ty) * (1.0f - tx), w01 = (1.0f - ty) * tx;
      float w10 = ty * (1.0f - tx),          w11 = ty * tx;
      int gc = g * 8;
      float4 s0 = {0.f, 0.f, 0.f, 0.f}, s1 = {0.f, 0.f, 0.f, 0.f};
#define CORNER(yy, xx, wgt)                                                     \
      if ((unsigned)(yy) < (unsigned)HY && (unsigned)(xx) < (unsigned)WY) {     \
        const float* p = ytb + ((size_t)((yy) * WY + (xx))) * 64 + gc;          \
        float4 c0 = *(const float4*)p;                                          \
        float4 c1 = *(const float4*)(p + 4);                                    \
        s0.x += (wgt) * c0.x; s0.y += (wgt) * c0.y;                             \
        s0.z += (wgt) * c0.z; s0.w += (wgt) * c0.w;                             \
        s1.x += (wgt) * c1.x; s1.y += (wgt) * c1.y;                             \
        s1.z += (wgt) * c1.z; s1.w += (wgt) * c1.w;                             \
      }
      CORNER(y0, x0, w00)
      CORNER(y0, x1, w01)
      CORNER(y1, x0, w10)
      CORNER(y1, x1, w11)
#undef CORNER
      sval[(gc + 0) * 68 + gpx] = s0.x * m;
      sval[(gc + 1) * 68 + gpx] = s0.y * m;
      sval[(gc + 2) * 68 + gpx] = s0.z * m;
      sval[(gc + 3) * 68 + gpx] = s0.w * m;
      sval[(gc + 4) * 68 + gpx] = s1.x * m;
      sval[(gc + 5) * 68 + gpx] = s1.y * m;
      sval[(gc + 6) * 68 + gpx] = s1.z * m;
      sval[(gc + 7) * 68 + gpx] = s1.w * m;
    }
    __syncthreads();
    const float* wk = wt1 + k * 64 * 64;
#pragma unroll 4
    for (int c = 0; c < 64; ++c) {
      float4 wv = *(const float4*)&wk[c * 64 + 4 * ocq];
      float4 vv = *(const float4*)&sval[c * 68 + 4 * pxq];
      acc[0][0] += wv.x * vv.x; acc[0][1] += wv.x * vv.y;
      acc[0][2] += wv.x * vv.z; acc[0][3] += wv.x * vv.w;
      acc[1][0] += wv.y * vv.x; acc[1][1] += wv.y * vv.y;
      acc[1][2] += wv.y * vv.z; acc[1][3] += wv.y * vv.w;
      acc[2][0] += wv.z * vv.x; acc[2][1] += wv.z * vv.y;
      acc[2][2] += wv.z * vv.z; acc[2][3] += wv.z * vv.w;
      acc[3][0] += wv.w * vv.x; acc[3][1] += wv.w * vv.y;
      acc[3][2] += wv.w * vv.z; acc[3][3] += wv.w * vv.w;
    }
  }
  // epilogue: bias + relu + store
  int py_ = pxq >> 1;
  int colb = (pxq & 1) * 4;
#pragma unroll
  for (int i = 0; i < 4; ++i) {
    int oc = 4 * ocq + i;
    float bv = bdc[oc];
    float4 o;
    o.x = fmaxf(acc[i][0] + bv, 0.0f);
    o.y = fmaxf(acc[i][1] + bv, 0.0f);
    o.z = fmaxf(acc[i][2] + bv, 0.0f);
    o.w = fmaxf(acc[i][3] + bv, 0.0f);
    *(float4*)&out[((size_t)(b * 64 + oc) * 96 + (h0 + py_)) * 96 + w0 + colb] = o;
  }
}

extern "C" void kernel_launch(void* const* d_in, const int* in_sizes, int n_in,
                              void* d_out, int out_size, void* d_ws, size_t ws_size,
                              hipStream_t stream) {
  const float* x = (const float*)d_in[0];
  const float* y = (const float*)d_in[1];
  const float* w_om = (const float*)d_in[2];
  const float* b_om = (const float*)d_in[3];
  const float* w_dc = (const float*)d_in[4];
  const float* b_dc = (const float*)d_in[5];
  float* out = (float*)d_out;

  float* om  = (float*)d_ws;                 // 4*216*2304 = 1,990,656 f
  float* wt2 = om + 1990656;                 // 147,456 f
  float* wt1 = wt2 + 147456;                 // 36,864 f
  float* yt  = wt1 + 36864;                  // 2,359,296 f  (total ~18.1 MB)

  prep_w_kernel<<<720, 256, 0, stream>>>(w_om, w_dc, wt2, wt1);
  ytr_kernel<<<576, 256, 0, stream>>>(y, yt);
  conv_gemm_kernel<<<576, 256, 0, stream>>>(x, wt2, b_om, om);
  deform_gemm_kernel<<<576, 256, 0, stream>>>(yt, om, wt1, b_dc, out);
}